// Round 2
// baseline (584.061 us; speedup 1.0000x reference)
//
#include <hip/hip_runtime.h>
#include <math.h>

#define EPS 1e-5f

// ---------------------------------------------------------------------------
// Deconv + GN stats. 128-thread blocks = 2 independent waves, 64 nodes/wave,
// lane owns 1 node (all 32 couts in registers). No barriers in the tap loop:
// each wave stages its X tile into a private LDS slice (same-wave DS ops are
// in-order). W[k][ci][co] is wave-uniform -> scalar loads + v_fmac with SGPR.
// ---------------------------------------------------------------------------
__global__ __launch_bounds__(128, 4) void deconv_stats_kernel(
    const float* __restrict__ data, const float* __restrict__ W,
    const int* __restrict__ neigh, const int* __restrict__ batch_id,
    float* __restrict__ out, float* __restrict__ gs1, float* __restrict__ gs2,
    float* __restrict__ gcnt, int N)
{
    __shared__ float XT[2][32][64];   // [wave][ci][node] : 16 KB
    __shared__ float ls1[256];        // per-(batch,ch) sum h
    __shared__ float ls2[256];        // per-(batch,ch) sum h^2
    __shared__ float lcnt[8];

    const int t  = threadIdx.x;
    const int wv = t >> 6;            // wave id 0/1
    const int ln = t & 63;            // lane = local node
    const int gm = blockIdx.x * 128 + wv * 64 + ln;   // global node
    const bool valid = gm < N;

    ls1[t] = 0.f; ls1[t + 128] = 0.f;
    ls2[t] = 0.f; ls2[t + 128] = 0.f;
    if (t < 8) lcnt[t] = 0.f;
    __syncthreads();                  // only barrier before the end

    const long row = (long)(valid ? gm : (N - 1)) * 27;

    float acc[32];
#pragma unroll
    for (int c = 0; c < 32; ++c) acc[c] = 0.f;

    // index pipeline (2-deep) + gather of tap 0
    int ng      = neigh[row];         // tap 0
    int idx_nxt = neigh[row + 1];     // tap 1
    float4 xr[8];
    {
        const float4* gp = (const float4*)(data + (size_t)ng * 32);
#pragma unroll
        for (int q = 0; q < 8; ++q) xr[q] = gp[q];
    }

    for (int k = 0; k < 27; ++k) {
        // write x(k) into this wave's LDS column (waits on gather vmcnt only)
#pragma unroll
        for (int q = 0; q < 8; ++q) {
            XT[wv][4 * q + 0][ln] = xr[q].x;
            XT[wv][4 * q + 1][ln] = xr[q].y;
            XT[wv][4 * q + 2][ln] = xr[q].z;
            XT[wv][4 * q + 3][ln] = xr[q].w;
        }
        // prefetch gather for tap k+1 (full tap of compute to cover latency)
        if (k < 26) {
            ng = idx_nxt;
            idx_nxt = neigh[row + (k + 2 <= 26 ? k + 2 : 26)];
            const float4* gp = (const float4*)(data + (size_t)ng * 32);
#pragma unroll
            for (int q = 0; q < 8; ++q) xr[q] = gp[q];
        }
        // compute: x from LDS (b32, conflict-free), w wave-uniform (SGPR)
        const float* Wk = W + k * 1024;
#pragma unroll
        for (int ci = 0; ci < 32; ++ci) {
            const float xv = XT[wv][ci][ln];
            const float* wp = Wk + ci * 32;
#pragma unroll
            for (int co = 0; co < 32; ++co)
                acc[co] = fmaf(xv, wp[co], acc[co]);
        }
    }

    // epilogue: store pre-norm h + accumulate GN stats
    if (valid) {
        const int b = batch_id[gm];
        float* op = out + (size_t)gm * 32;
#pragma unroll
        for (int q = 0; q < 8; ++q)
            ((float4*)op)[q] = make_float4(acc[4 * q + 0], acc[4 * q + 1],
                                           acc[4 * q + 2], acc[4 * q + 3]);
        // staggered channels: each step hits 32 distinct banks, 2-way max
#pragma unroll
        for (int cc = 0; cc < 32; ++cc) {
            const int c = (cc + ln) & 31;
            const float v = acc[c];
            atomicAdd(&ls1[b * 32 + c], v);
            atomicAdd(&ls2[b * 32 + c], v * v);
        }
        atomicAdd(&lcnt[b], 1.0f);
    }
    __syncthreads();

    {
        float v;
        v = ls1[t];       if (v != 0.f) atomicAdd(&gs1[t], v);
        v = ls1[t + 128]; if (v != 0.f) atomicAdd(&gs1[t + 128], v);
        v = ls2[t];       if (v != 0.f) atomicAdd(&gs2[t], v);
        v = ls2[t + 128]; if (v != 0.f) atomicAdd(&gs2[t + 128], v);
        if (t < 8) { v = lcnt[t]; if (v != 0.f) atomicAdd(&gcnt[t], v); }
    }
}

// ---------------------------------------------------------------------------
// GN finalize folded into apply: thread handles one (node, 4-ch group) quad.
// Groups of 4 channels align exactly with float4 quads (C/G = 4).
// ---------------------------------------------------------------------------
__global__ __launch_bounds__(256) void gn_relu_kernel(
    float* __restrict__ out, const int* __restrict__ batch_id,
    const float* __restrict__ gs1, const float* __restrict__ gs2,
    const float* __restrict__ gcnt, const float* __restrict__ gamma,
    const float* __restrict__ beta, int N)
{
    const int idx = blockIdx.x * 256 + threadIdx.x;
    if (idx >= N * 8) return;
    const int n = idx >> 3;           // node
    const int g = idx & 7;            // group = channel quad
    const int b = batch_id[n];

    const float cnt  = gcnt[b] * 4.0f;          // n_nodes * C/G
    const float icnt = 1.0f / (cnt + EPS);
    const float4 s1 = *(const float4*)(gs1 + b * 32 + g * 4);
    const float4 s2 = *(const float4*)(gs2 + b * 32 + g * 4);
    const float S1 = s1.x + s1.y + s1.z + s1.w;
    const float S2 = s2.x + s2.y + s2.z + s2.w;
    const float m   = S1 * icnt;
    const float var = (S2 - 2.0f * m * S1 + cnt * m * m) * icnt;
    const float istd = rsqrtf(var + EPS);

    const float4 gm4 = *(const float4*)(gamma + g * 4);
    const float4 bt4 = *(const float4*)(beta + g * 4);
    float4 h = *(float4*)(out + (size_t)idx * 4);
    h.x = fmaxf((h.x - m) * istd * gm4.x + bt4.x, 0.f);
    h.y = fmaxf((h.y - m) * istd * gm4.y + bt4.y, 0.f);
    h.z = fmaxf((h.z - m) * istd * gm4.z + bt4.z, 0.f);
    h.w = fmaxf((h.w - m) * istd * gm4.w + bt4.w, 0.f);
    *(float4*)(out + (size_t)idx * 4) = h;
}

// ---------------------------------------------------------------------------
extern "C" void kernel_launch(void* const* d_in, const int* in_sizes, int n_in,
                              void* d_out, int out_size, void* d_ws, size_t ws_size,
                              hipStream_t stream) {
    const float* data     = (const float*)d_in[0];   // [N,32]
    const float* weights  = (const float*)d_in[1];   // [27,32,32]
    const float* gamma    = (const float*)d_in[2];   // [32]
    const float* beta     = (const float*)d_in[3];   // [32]
    const int*   neigh    = (const int*)d_in[4];     // [N,27]
    const int*   batch_id = (const int*)d_in[5];     // [N]
    const int N = in_sizes[0] / 32;
    float* out = (float*)d_out;

    // workspace: gs1[256] gs2[256] gcnt[8]
    float* ws = (float*)d_ws;
    float* gs1  = ws;
    float* gs2  = ws + 256;
    float* gcnt = ws + 512;
    hipMemsetAsync(ws, 0, 520 * sizeof(float), stream);

    const int nblocks = (N + 127) / 128;
    hipLaunchKernelGGL(deconv_stats_kernel, dim3(nblocks), dim3(128), 0, stream,
                       data, weights, neigh, batch_id, out, gs1, gs2, gcnt, N);

    const int n8 = N * 8;
    hipLaunchKernelGGL(gn_relu_kernel, dim3((n8 + 255) / 256), dim3(256), 0,
                       stream, out, batch_id, gs1, gs2, gcnt, gamma, beta, N);
}

// Round 3
// 568.221 us; speedup vs baseline: 1.0279x; 1.0279x over previous
//
#include <hip/hip_runtime.h>
#include <math.h>

#define EPS 1e-5f

// ---------------------------------------------------------------------------
// Deconv + GN stats. 256-thread blocks, lane owns one node: all 32 couts in
// acc registers, gathered X row lives in registers (NO LDS in the tap loop).
// Double-buffered gather: compute tap k from xc while tap k+1 streams into xn.
// W[k][ci][co] is wave-uniform -> scalarized s_loads, v_fmac with SGPR src.
// lgkmcnt now tracks ONLY smem (W); vmcnt ONLY the 8 gather loads per tap.
// ---------------------------------------------------------------------------
__global__ __launch_bounds__(256, 4) void deconv_stats_kernel(
    const float* __restrict__ data, const float* __restrict__ W,
    const int* __restrict__ neigh, const int* __restrict__ batch_id,
    float* __restrict__ out, float* __restrict__ gs1, float* __restrict__ gs2,
    float* __restrict__ gcnt, int N)
{
    __shared__ float ls1[256];        // per-(batch,ch) sum h
    __shared__ float ls2[256];        // per-(batch,ch) sum h^2
    __shared__ float lcnt[8];

    const int t  = threadIdx.x;
    const int ln = t & 63;
    const int gm = blockIdx.x * 256 + t;          // global node
    const bool valid = gm < N;

    ls1[t] = 0.f;
    ls2[t] = 0.f;
    if (t < 8) lcnt[t] = 0.f;
    __syncthreads();                  // stats buffers ready (only barrier until epilogue)

    const long row = (long)(valid ? gm : (N - 1)) * 27;

    float acc[32];
#pragma unroll
    for (int c = 0; c < 32; ++c) acc[c] = 0.f;

    // gather pipeline: xc = tap k (being consumed), xn = tap k+1 (in flight)
    float4 xc[8], xn[8];
    {
        const int ng0 = neigh[row];
        const float4* gp = (const float4*)(data + (size_t)ng0 * 32);
#pragma unroll
        for (int q = 0; q < 8; ++q) xc[q] = gp[q];
    }
    int nidx = neigh[row + 1];        // index of tap 1

#pragma unroll 1                      // keep one copy of the 1024-FMA body
    for (int k = 0; k < 27; ++k) {
        if (k < 26) {                 // issue gather for tap k+1 (8 loads, no wait)
            const float4* gp = (const float4*)(data + (size_t)nidx * 32);
            nidx = neigh[row + (k + 2 < 27 ? k + 2 : 26)];
#pragma unroll
            for (int q = 0; q < 8; ++q) xn[q] = gp[q];
        }
        const float* Wk = W + k * 1024;
#pragma unroll
        for (int q = 0; q < 8; ++q) {
            const float xs0 = xc[q].x, xs1 = xc[q].y, xs2 = xc[q].z, xs3 = xc[q].w;
            const float* wp = Wk + q * 128;
#pragma unroll
            for (int co = 0; co < 32; ++co)
                acc[co] = fmaf(xs0, wp[co], acc[co]);
#pragma unroll
            for (int co = 0; co < 32; ++co)
                acc[co] = fmaf(xs1, wp[32 + co], acc[co]);
#pragma unroll
            for (int co = 0; co < 32; ++co)
                acc[co] = fmaf(xs2, wp[64 + co], acc[co]);
#pragma unroll
            for (int co = 0; co < 32; ++co)
                acc[co] = fmaf(xs3, wp[96 + co], acc[co]);
        }
        // rotate buffers (compiler renames after unroll-by-? ; worst case 32 movs)
#pragma unroll
        for (int q = 0; q < 8; ++q) xc[q] = xn[q];
    }

    // epilogue: store pre-norm h + accumulate GN stats (staggered channels ->
    // each step hits 32 distinct banks; measured 0 conflicts in round 1)
    if (valid) {
        const int b = batch_id[gm];
        float* op = out + (size_t)gm * 32;
#pragma unroll
        for (int q = 0; q < 8; ++q)
            ((float4*)op)[q] = make_float4(acc[4 * q + 0], acc[4 * q + 1],
                                           acc[4 * q + 2], acc[4 * q + 3]);
#pragma unroll
        for (int cc = 0; cc < 32; ++cc) {
            const int c = (cc + ln) & 31;
            const float v = acc[c];
            atomicAdd(&ls1[b * 32 + c], v);
            atomicAdd(&ls2[b * 32 + c], v * v);
        }
        atomicAdd(&lcnt[b], 1.0f);
    }
    __syncthreads();

    {
        float v;
        v = ls1[t]; if (v != 0.f) atomicAdd(&gs1[t], v);
        v = ls2[t]; if (v != 0.f) atomicAdd(&gs2[t], v);
        if (t < 8) { v = lcnt[t]; if (v != 0.f) atomicAdd(&gcnt[t], v); }
    }
}

// ---------------------------------------------------------------------------
// GN finalize + apply + ReLU: thread handles one (node, 4-ch group) quad.
// Groups of 4 channels align exactly with float4 quads (C/G = 4).
// ---------------------------------------------------------------------------
__global__ __launch_bounds__(256) void gn_relu_kernel(
    float* __restrict__ out, const int* __restrict__ batch_id,
    const float* __restrict__ gs1, const float* __restrict__ gs2,
    const float* __restrict__ gcnt, const float* __restrict__ gamma,
    const float* __restrict__ beta, int N)
{
    const int idx = blockIdx.x * 256 + threadIdx.x;
    if (idx >= N * 8) return;
    const int n = idx >> 3;           // node
    const int g = idx & 7;            // group = channel quad
    const int b = batch_id[n];

    const float cnt  = gcnt[b] * 4.0f;          // n_nodes * C/G
    const float icnt = 1.0f / (cnt + EPS);
    const float4 s1 = *(const float4*)(gs1 + b * 32 + g * 4);
    const float4 s2 = *(const float4*)(gs2 + b * 32 + g * 4);
    const float S1 = s1.x + s1.y + s1.z + s1.w;
    const float S2 = s2.x + s2.y + s2.z + s2.w;
    const float m   = S1 * icnt;
    const float var = (S2 - 2.0f * m * S1 + cnt * m * m) * icnt;
    const float istd = rsqrtf(var + EPS);

    const float4 gm4 = *(const float4*)(gamma + g * 4);
    const float4 bt4 = *(const float4*)(beta + g * 4);
    float4 h = *(float4*)(out + (size_t)idx * 4);
    h.x = fmaxf((h.x - m) * istd * gm4.x + bt4.x, 0.f);
    h.y = fmaxf((h.y - m) * istd * gm4.y + bt4.y, 0.f);
    h.z = fmaxf((h.z - m) * istd * gm4.z + bt4.z, 0.f);
    h.w = fmaxf((h.w - m) * istd * gm4.w + bt4.w, 0.f);
    *(float4*)(out + (size_t)idx * 4) = h;
}

// ---------------------------------------------------------------------------
extern "C" void kernel_launch(void* const* d_in, const int* in_sizes, int n_in,
                              void* d_out, int out_size, void* d_ws, size_t ws_size,
                              hipStream_t stream) {
    const float* data     = (const float*)d_in[0];   // [N,32]
    const float* weights  = (const float*)d_in[1];   // [27,32,32]
    const float* gamma    = (const float*)d_in[2];   // [32]
    const float* beta     = (const float*)d_in[3];   // [32]
    const int*   neigh    = (const int*)d_in[4];     // [N,27]
    const int*   batch_id = (const int*)d_in[5];     // [N]
    const int N = in_sizes[0] / 32;
    float* out = (float*)d_out;

    // workspace: gs1[256] gs2[256] gcnt[8]
    float* ws = (float*)d_ws;
    float* gs1  = ws;
    float* gs2  = ws + 256;
    float* gcnt = ws + 512;
    hipMemsetAsync(ws, 0, 520 * sizeof(float), stream);

    const int nblocks = (N + 255) / 256;
    hipLaunchKernelGGL(deconv_stats_kernel, dim3(nblocks), dim3(256), 0, stream,
                       data, weights, neigh, batch_id, out, gs1, gs2, gcnt, N);

    const int n8 = N * 8;
    hipLaunchKernelGGL(gn_relu_kernel, dim3((n8 + 255) / 256), dim3(256), 0,
                       stream, out, batch_id, gs1, gs2, gcnt, gamma, beta, N);
}